// Round 1
// baseline (926.054 us; speedup 1.0000x reference)
//
#include <hip/hip_runtime.h>
#include <hip/hip_bf16.h>
#include <math.h>

// Problem constants (from reference)
#define NN 50000
#define EE 800000
#define DIN 128
#define HID 256
#define NCLS 16
#define NPROT 512

// ---------------- degree / CSR construction ----------------

__global__ __launch_bounds__(256) void k_count(const int* __restrict__ dst, int* __restrict__ cnt, int e) {
    int i = blockIdx.x * 256 + threadIdx.x;
    if (i < e) atomicAdd(&cnt[dst[i]], 1);
}

__global__ __launch_bounds__(256) void k_dis(const int* __restrict__ cnt, float* __restrict__ dis, int n) {
    int i = blockIdx.x * 256 + threadIdx.x;
    if (i < n) dis[i] = rsqrtf((float)cnt[i] + 1.0f);  // +1 self loop
}

__global__ __launch_bounds__(256) void k_scan1(const int* __restrict__ cnt, int* __restrict__ excl,
                                               int* __restrict__ bsum, int n) {
    __shared__ int s[256];
    int t = threadIdx.x;
    int i = blockIdx.x * 256 + t;
    int v = (i < n) ? cnt[i] : 0;
    s[t] = v; __syncthreads();
    for (int d = 1; d < 256; d <<= 1) {
        int add = (t >= d) ? s[t - d] : 0;
        __syncthreads();
        s[t] += add;
        __syncthreads();
    }
    if (i < n) excl[i] = s[t] - v;
    if (t == 255) bsum[blockIdx.x] = s[255];
}

__global__ __launch_bounds__(256) void k_scan2(const int* __restrict__ bsum, int* __restrict__ boff, int nb) {
    __shared__ int s[256];
    int t = threadIdx.x;
    int v = (t < nb) ? bsum[t] : 0;
    s[t] = v; __syncthreads();
    for (int d = 1; d < 256; d <<= 1) {
        int add = (t >= d) ? s[t - d] : 0;
        __syncthreads();
        s[t] += add;
        __syncthreads();
    }
    if (t < nb) boff[t] = s[t] - v;
}

__global__ __launch_bounds__(256) void k_scan3(const int* __restrict__ excl, const int* __restrict__ boff,
                                               int* __restrict__ off, int n, int e) {
    int i = blockIdx.x * 256 + threadIdx.x;
    if (i < n) off[i] = excl[i] + boff[blockIdx.x];
    if (i == 0) off[n] = e;
}

__global__ __launch_bounds__(256) void k_fill(const int* __restrict__ src, const int* __restrict__ dst,
                                              const int* __restrict__ off, int* __restrict__ cursor,
                                              const float* __restrict__ dis,
                                              int* __restrict__ csr_src, float* __restrict__ csr_norm, int e) {
    int i = blockIdx.x * 256 + threadIdx.x;
    if (i >= e) return;
    int s = src[i], d = dst[i];
    int pos = atomicAdd(&cursor[d], 1);
    int slot = off[d] + pos;
    csr_src[slot] = s;
    csr_norm[slot] = dis[s] * dis[d];
}

// ---------------- fp32 GEMM: C[M,N] = A[M,K] @ B[K,N] (+ optional cosine scale epilogue) ----------------

__global__ __launch_bounds__(256) void k_gemm64(const float* __restrict__ A, const float* __restrict__ B,
                                                float* __restrict__ C, int M, int N, int K,
                                                const float* __restrict__ rowscale,
                                                const float* __restrict__ colscale) {
    __shared__ __align__(16) float As[16][68];
    __shared__ __align__(16) float Bs[16][64];
    const int tid = threadIdx.x;
    const int tx = tid & 15, ty = tid >> 4;
    const int row0 = blockIdx.y * 64, col0 = blockIdx.x * 64;
    float c[4][4] = {};
    const int ar = row0 + (tid >> 2);
    const int ak = (tid & 3) * 4;
    const int bk = tid >> 4;
    const int bc = col0 + (tid & 15) * 4;

    for (int k0 = 0; k0 < K; k0 += 16) {
        float4 av = make_float4(0.f, 0.f, 0.f, 0.f);
        if (ar < M) av = *reinterpret_cast<const float4*>(A + (size_t)ar * K + k0 + ak);
        float4 bv = *reinterpret_cast<const float4*>(B + (size_t)(k0 + bk) * N + bc);
        As[ak + 0][tid >> 2] = av.x;
        As[ak + 1][tid >> 2] = av.y;
        As[ak + 2][tid >> 2] = av.z;
        As[ak + 3][tid >> 2] = av.w;
        *reinterpret_cast<float4*>(&Bs[bk][(tid & 15) * 4]) = bv;
        __syncthreads();
#pragma unroll
        for (int kk = 0; kk < 16; ++kk) {
            float a[4], b[4];
#pragma unroll
            for (int i = 0; i < 4; ++i) a[i] = As[kk][ty * 4 + i];
#pragma unroll
            for (int j = 0; j < 4; ++j) b[j] = Bs[kk][tx * 4 + j];
#pragma unroll
            for (int i = 0; i < 4; ++i)
#pragma unroll
                for (int j = 0; j < 4; ++j) c[i][j] = fmaf(a[i], b[j], c[i][j]);
        }
        __syncthreads();
    }

#pragma unroll
    for (int i = 0; i < 4; ++i) {
        int r = row0 + ty * 4 + i;
        if (r >= M) break;
        float rs = rowscale ? rowscale[r] : 1.0f;
#pragma unroll
        for (int j = 0; j < 4; ++j) {
            int cc = col0 + tx * 4 + j;
            float v = c[i][j];
            if (colscale) v = v / fmaxf(rs * colscale[cc], 1e-6f);
            C[(size_t)r * N + cc] = v;
        }
    }
}

// ---------------- GCN aggregation: one wave per node over CSR in-edges ----------------

__global__ __launch_bounds__(256) void k_agg(const float* __restrict__ xw, const int* __restrict__ off,
                                             const int* __restrict__ esrc, const float* __restrict__ enorm,
                                             const float* __restrict__ dis, const float* __restrict__ bias,
                                             float* __restrict__ out, int n, int do_relu) {
    int wave = (blockIdx.x * 256 + threadIdx.x) >> 6;
    int lane = threadIdx.x & 63;
    if (wave >= n) return;
    int colb = lane * 4;
    float d = dis[wave];
    float w0 = d * d;  // self-loop norm
    float4 v = *reinterpret_cast<const float4*>(xw + (size_t)wave * HID + colb);
    float4 acc;
    acc.x = w0 * v.x; acc.y = w0 * v.y; acc.z = w0 * v.z; acc.w = w0 * v.w;
    int p0 = off[wave], p1 = off[wave + 1];
    for (int p = p0; p < p1; ++p) {
        int s = esrc[p];
        float w = enorm[p];
        float4 u = *reinterpret_cast<const float4*>(xw + (size_t)s * HID + colb);
        acc.x = fmaf(w, u.x, acc.x);
        acc.y = fmaf(w, u.y, acc.y);
        acc.z = fmaf(w, u.z, acc.z);
        acc.w = fmaf(w, u.w, acc.w);
    }
    float4 b = *reinterpret_cast<const float4*>(bias + colb);
    acc.x += b.x; acc.y += b.y; acc.z += b.z; acc.w += b.w;
    if (do_relu) {
        acc.x = fmaxf(acc.x, 0.f); acc.y = fmaxf(acc.y, 0.f);
        acc.z = fmaxf(acc.z, 0.f); acc.w = fmaxf(acc.w, 0.f);
    }
    *reinterpret_cast<float4*>(out + (size_t)wave * HID + colb) = acc;
}

// ---------------- L2 row-normalize (in place) + recomputed row norm nx ----------------

__global__ __launch_bounds__(256) void k_norm(float* __restrict__ h, float* __restrict__ nx, int n) {
    int wave = (blockIdx.x * 256 + threadIdx.x) >> 6;
    int lane = threadIdx.x & 63;
    if (wave >= n) return;
    float4* row = reinterpret_cast<float4*>(h + (size_t)wave * HID);
    float4 v = row[lane];
    float ss = v.x * v.x + v.y * v.y + v.z * v.z + v.w * v.w;
    for (int m = 32; m >= 1; m >>= 1) ss += __shfl_xor(ss, m, 64);
    float qn = sqrtf(ss);
    float4 hn;
    hn.x = v.x / qn; hn.y = v.y / qn; hn.z = v.z / qn; hn.w = v.w / qn;
    float s2 = hn.x * hn.x + hn.y * hn.y + hn.z * hn.z + hn.w * hn.w;
    for (int m = 32; m >= 1; m >>= 1) s2 += __shfl_xor(s2, m, 64);
    row[lane] = hn;
    if (lane == 0) nx[wave] = sqrtf(s2);
}

// ---------------- anchor gather: row-major copy + transposed copy + anchor norms ----------------

__global__ __launch_bounds__(256) void k_gather(const float* __restrict__ h, const int* __restrict__ prot,
                                                const float* __restrict__ nx,
                                                float* __restrict__ aR, float* __restrict__ aT,
                                                float* __restrict__ na, int p_cnt) {
    int wave = (blockIdx.x * 256 + threadIdx.x) >> 6;
    int lane = threadIdx.x & 63;
    if (wave >= p_cnt) return;
    int p = prot[wave];
    float4 v = *reinterpret_cast<const float4*>(h + (size_t)p * HID + lane * 4);
    *reinterpret_cast<float4*>(aR + (size_t)wave * HID + lane * 4) = v;
    aT[(lane * 4 + 0) * NPROT + wave] = v.x;
    aT[(lane * 4 + 1) * NPROT + wave] = v.y;
    aT[(lane * 4 + 2) * NPROT + wave] = v.z;
    aT[(lane * 4 + 3) * NPROT + wave] = v.w;
    if (lane == 0) na[wave] = nx[p];
}

// ---------------- prototype head: out_proto = log_softmax(relu(anchors@Wl1+bl1)@Wl2+bl2) ----------------

__global__ __launch_bounds__(256) void k_proto(const float* __restrict__ aR, const float* __restrict__ Wl1,
                                               const float* __restrict__ bl1, const float* __restrict__ Wl2,
                                               const float* __restrict__ bl2, float* __restrict__ outp) {
    __shared__ float sa[HID];
    __shared__ float st[HID];
    int row = blockIdx.x, t = threadIdx.x;
    sa[t] = aR[(size_t)row * HID + t];
    __syncthreads();
    float acc = bl1[t];
#pragma unroll 8
    for (int k = 0; k < HID; ++k) acc = fmaf(sa[k], Wl1[k * HID + t], acc);
    st[t] = fmaxf(acc, 0.0f);
    __syncthreads();
    if (t < 64) {
        int c = t & 15, ch = t >> 4;
        float z = 0.f;
#pragma unroll 8
        for (int k = ch * 64; k < ch * 64 + 64; ++k) z = fmaf(st[k], Wl2[k * NCLS + c], z);
        z += __shfl_xor(z, 16, 64);
        z += __shfl_xor(z, 32, 64);
        z += bl2[c];
        float m = z;
        for (int d = 8; d >= 1; d >>= 1) m = fmaxf(m, __shfl_xor(m, d, 64));
        float e = expf(z - m);
        float s = e;
        for (int d = 8; d >= 1; d >>= 1) s += __shfl_xor(s, d, 64);
        if (t < 16) outp[row * NCLS + c] = z - m - logf(s);
    }
}

// ---------------- final: out = log_softmax(x_rel @ out_proto) ----------------

__global__ __launch_bounds__(256) void k_out(const float* __restrict__ xrel, const float* __restrict__ proto,
                                             float* __restrict__ out, int n) {
    __shared__ float sp[NPROT * NCLS];  // 32 KB
    int t = threadIdx.x;
    for (int i = t; i < NPROT * NCLS; i += 256) sp[i] = proto[i];
    __syncthreads();
    int c = t & 15, nl = t >> 4;
    int node = blockIdx.x * 16 + nl;
    const float* xr = xrel + (size_t)node * NPROT;
    float acc = 0.f;
#pragma unroll 4
    for (int p = 0; p < NPROT; ++p) acc = fmaf(xr[p], sp[p * NCLS + c], acc);
    float m = acc;
    for (int d = 8; d >= 1; d >>= 1) m = fmaxf(m, __shfl_xor(m, d, 64));
    float e = expf(acc - m);
    float s = e;
    for (int d = 8; d >= 1; d >>= 1) s += __shfl_xor(s, d, 64);
    out[(size_t)node * NCLS + c] = acc - m - logf(s);
}

// ---------------- launch ----------------

extern "C" void kernel_launch(void* const* d_in, const int* in_sizes, int n_in,
                              void* d_out, int out_size, void* d_ws, size_t ws_size,
                              hipStream_t stream) {
    const float* x    = (const float*)d_in[0];
    const int*   eidx = (const int*)d_in[1];
    const int*   prot = (const int*)d_in[2];
    // d_in[3] = epoch (unused on this branch)
    const float* W0  = (const float*)d_in[4];
    const float* b0  = (const float*)d_in[5];
    const float* W1  = (const float*)d_in[6];
    const float* b1  = (const float*)d_in[7];
    const float* Wl1 = (const float*)d_in[8];
    const float* bl1 = (const float*)d_in[9];
    const float* Wl2 = (const float*)d_in[10];
    const float* bl2 = (const float*)d_in[11];

    const int N = NN, E = EE;
    const int* esrc_in = eidx;
    const int* edst_in = eidx + E;

    // d_out layout: out [N,16] | x_rel [N,512] | out_proto [512,16]
    float* out_final = (float*)d_out;
    float* x_rel     = (float*)d_out + (size_t)N * NCLS;
    float* out_proto = x_rel + (size_t)N * NPROT;

    // workspace carve-out (bufA aliases into the x_rel output region: dead before x_rel is written)
    char* w = (char*)d_ws;
    auto alloc = [&](size_t bytes) { char* p = w; w += (bytes + 255) & ~(size_t)255; return p; };
    float* bufB     = (float*)alloc((size_t)N * HID * 4);   // h0 / h1 / h
    int*   cnt      = (int*)alloc((size_t)N * 4);
    int*   cursor   = (int*)alloc((size_t)N * 4);
    float* dis      = (float*)alloc((size_t)N * 4);
    int*   excl     = (int*)alloc((size_t)N * 4);
    int*   csr_off  = (int*)alloc((size_t)(N + 1) * 4);
    int*   bsum     = (int*)alloc(1024);
    int*   boff     = (int*)alloc(1024);
    int*   csr_src  = (int*)alloc((size_t)E * 4);
    float* csr_norm = (float*)alloc((size_t)E * 4);
    float* aR       = (float*)alloc((size_t)NPROT * HID * 4);
    float* aT       = (float*)alloc((size_t)HID * NPROT * 4);
    float* nx       = (float*)alloc((size_t)N * 4);
    float* na       = (float*)alloc((size_t)NPROT * 4);
    float* bufA     = x_rel;  // [N,256] fits in [N,512] region

    hipMemsetAsync(cnt, 0, (size_t)N * 4, stream);
    hipMemsetAsync(cursor, 0, (size_t)N * 4, stream);

    // CSR build
    k_count<<<(E + 255) / 256, 256, 0, stream>>>(edst_in, cnt, E);
    k_dis<<<(N + 255) / 256, 256, 0, stream>>>(cnt, dis, N);
    int NB = (N + 255) / 256;  // 196 <= 256
    k_scan1<<<NB, 256, 0, stream>>>(cnt, excl, bsum, N);
    k_scan2<<<1, 256, 0, stream>>>(bsum, boff, NB);
    k_scan3<<<NB, 256, 0, stream>>>(excl, boff, csr_off, N, E);
    k_fill<<<(E + 255) / 256, 256, 0, stream>>>(esrc_in, edst_in, csr_off, cursor, dis, csr_src, csr_norm, E);

    // layer 1: h0 = relu(agg(x@W0) + b0)
    dim3 gA(HID / 64, (N + 63) / 64);
    k_gemm64<<<gA, 256, 0, stream>>>(x, W0, bufA, N, HID, DIN, nullptr, nullptr);
    k_agg<<<N / 4, 256, 0, stream>>>(bufA, csr_off, csr_src, csr_norm, dis, b0, bufB, N, 1);

    // layer 2: h1 = agg(h0@W1) + b1
    k_gemm64<<<gA, 256, 0, stream>>>(bufB, W1, bufA, N, HID, HID, nullptr, nullptr);
    k_agg<<<N / 4, 256, 0, stream>>>(bufA, csr_off, csr_src, csr_norm, dis, b1, bufB, N, 0);

    // normalize + anchors
    k_norm<<<N / 4, 256, 0, stream>>>(bufB, nx, N);
    k_gather<<<NPROT / 4, 256, 0, stream>>>(bufB, prot, nx, aR, aT, na, NPROT);

    // x_rel = (h @ anchors^T) / max(nx*na, eps)   (writes over bufA region — bufA is dead)
    dim3 gR(NPROT / 64, (N + 63) / 64);
    k_gemm64<<<gR, 256, 0, stream>>>(bufB, aT, x_rel, N, NPROT, HID, nx, na);

    // prototype head + final composition
    k_proto<<<NPROT, 256, 0, stream>>>(aR, Wl1, bl1, Wl2, bl2, out_proto);
    k_out<<<N / 16, 256, 0, stream>>>(x_rel, out_proto, out_final, N);
}

// Round 2
// 607.439 us; speedup vs baseline: 1.5245x; 1.5245x over previous
//
#include <hip/hip_runtime.h>
#include <hip/hip_bf16.h>
#include <math.h>

#define NN 50000
#define NP 50048          // padded to 128-multiple for MFMA tiles
#define EE 800000
#define DIN 128
#define HID 256
#define NCLS 16
#define NPROT 512

typedef __attribute__((ext_vector_type(8))) short short8;
typedef __attribute__((ext_vector_type(4))) float f32x4;

__device__ inline unsigned short f2b(float f) {
    union { float f; unsigned u; } c; c.f = f;
    unsigned u = c.u;
    unsigned r = (u + 0x7FFFu + ((u >> 16) & 1u)) >> 16;
    return (unsigned short)r;
}
__device__ inline float b2f(unsigned short u) {
    union { unsigned u; float f; } c; c.u = ((unsigned)u) << 16; return c.f;
}

// ---------------- degree / CSR construction ----------------

__global__ __launch_bounds__(256) void k_count(const int* __restrict__ dst, int* __restrict__ cnt, int e) {
    int i = blockIdx.x * 256 + threadIdx.x;
    if (i < e) atomicAdd(&cnt[dst[i]], 1);
}

__global__ __launch_bounds__(256) void k_dis(const int* __restrict__ cnt, float* __restrict__ dis, int n) {
    int i = blockIdx.x * 256 + threadIdx.x;
    if (i < n) dis[i] = rsqrtf((float)cnt[i] + 1.0f);
}

__global__ __launch_bounds__(256) void k_scan1(const int* __restrict__ cnt, int* __restrict__ excl,
                                               int* __restrict__ bsum, int n) {
    __shared__ int s[256];
    int t = threadIdx.x;
    int i = blockIdx.x * 256 + t;
    int v = (i < n) ? cnt[i] : 0;
    s[t] = v; __syncthreads();
    for (int d = 1; d < 256; d <<= 1) {
        int add = (t >= d) ? s[t - d] : 0;
        __syncthreads();
        s[t] += add;
        __syncthreads();
    }
    if (i < n) excl[i] = s[t] - v;
    if (t == 255) bsum[blockIdx.x] = s[255];
}

__global__ __launch_bounds__(256) void k_scan2(const int* __restrict__ bsum, int* __restrict__ boff, int nb) {
    __shared__ int s[256];
    int t = threadIdx.x;
    int v = (t < nb) ? bsum[t] : 0;
    s[t] = v; __syncthreads();
    for (int d = 1; d < 256; d <<= 1) {
        int add = (t >= d) ? s[t - d] : 0;
        __syncthreads();
        s[t] += add;
        __syncthreads();
    }
    if (t < nb) boff[t] = s[t] - v;
}

__global__ __launch_bounds__(256) void k_scan3(const int* __restrict__ excl, const int* __restrict__ boff,
                                               int* __restrict__ off, int n, int e) {
    int i = blockIdx.x * 256 + threadIdx.x;
    if (i < n) off[i] = excl[i] + boff[blockIdx.x];
    if (i == 0) off[n] = e;
}

__global__ __launch_bounds__(256) void k_fill(const int* __restrict__ src, const int* __restrict__ dst,
                                              const int* __restrict__ off, int* __restrict__ cursor,
                                              const float* __restrict__ dis,
                                              int* __restrict__ csr_src, float* __restrict__ csr_norm, int e) {
    int i = blockIdx.x * 256 + threadIdx.x;
    if (i >= e) return;
    int s = src[i], d = dst[i];
    int pos = atomicAdd(&cursor[d], 1);
    int slot = off[d] + pos;
    csr_src[slot] = s;
    csr_norm[slot] = dis[s] * dis[d];
}

// ---------------- casts / transposes ----------------

__global__ __launch_bounds__(256) void k_cast(const float* __restrict__ x, unsigned short* __restrict__ xb, int n4) {
    int i = blockIdx.x * 256 + threadIdx.x;
    if (i >= n4) return;
    float4 v = ((const float4*)x)[i];
    ushort4 o; o.x = f2b(v.x); o.y = f2b(v.y); o.z = f2b(v.z); o.w = f2b(v.w);
    ((ushort4*)xb)[i] = o;
}

// Wt[n*K+k] = bf16(W[k*N+n])
__global__ __launch_bounds__(256) void k_wt(const float* __restrict__ W, unsigned short* __restrict__ Wt,
                                            int K, int Nn) {
    int i = blockIdx.x * 256 + threadIdx.x;
    if (i >= K * Nn) return;
    int k = i / Nn, n = i - k * Nn;
    Wt[n * K + k] = f2b(W[(size_t)k * Nn + n]);
}

// ---------------- bf16 MFMA GEMM: C[M,Nc] = A[Mp,K] @ Bt[Nc,K]^T ----------------
// mode 0: store bf16 (unguarded, C padded).  mode 1: store fp32 with cosine scale, guarded r<M.

__global__ __launch_bounds__(256) void k_gemm_mfma(const unsigned short* __restrict__ A,
                                                   const unsigned short* __restrict__ Bt,
                                                   void* __restrict__ C, int M, int Nc, int K, int mode,
                                                   const float* __restrict__ nx, const float* __restrict__ na) {
    __shared__ __align__(16) unsigned short As[128 * 40];  // row stride 40 shorts (80B) to spread banks
    __shared__ __align__(16) unsigned short Bs[128 * 40];
    const int t = threadIdx.x;
    const int lane = t & 63;
    const int quad = lane >> 4;
    const int l16 = lane & 15;
    const int wv = t >> 6;
    const int wm = (wv & 1) * 64, wn = (wv >> 1) * 64;
    const int m0 = blockIdx.y * 128, n0 = blockIdx.x * 128;

    f32x4 acc[4][4];
#pragma unroll
    for (int i = 0; i < 4; ++i)
#pragma unroll
        for (int j = 0; j < 4; ++j)
#pragma unroll
            for (int r = 0; r < 4; ++r) acc[i][j][r] = 0.0f;

    const int sr = t >> 2;         // staging row 0..63 (per pass)
    const int sc = (t & 3) * 8;    // short offset in row: 0,8,16,24

    for (int k0 = 0; k0 < K; k0 += 32) {
#pragma unroll
        for (int p = 0; p < 2; ++p) {
            int r = p * 64 + sr;
            uint4 av = *(const uint4*)(A + (size_t)(m0 + r) * K + k0 + sc);
            uint4 bv = *(const uint4*)(Bt + (size_t)(n0 + r) * K + k0 + sc);
            *(uint4*)&As[r * 40 + sc] = av;
            *(uint4*)&Bs[r * 40 + sc] = bv;
        }
        __syncthreads();
        short8 af[4], bf[4];
#pragma unroll
        for (int i = 0; i < 4; ++i)
            af[i] = *(const short8*)&As[(wm + i * 16 + l16) * 40 + quad * 8];
#pragma unroll
        for (int j = 0; j < 4; ++j)
            bf[j] = *(const short8*)&Bs[(wn + j * 16 + l16) * 40 + quad * 8];
#pragma unroll
        for (int i = 0; i < 4; ++i)
#pragma unroll
            for (int j = 0; j < 4; ++j)
                acc[i][j] = __builtin_amdgcn_mfma_f32_16x16x32_bf16(af[i], bf[j], acc[i][j], 0, 0, 0);
        __syncthreads();
    }

#pragma unroll
    for (int i = 0; i < 4; ++i) {
        int rb = m0 + wm + i * 16 + quad * 4;
#pragma unroll
        for (int j = 0; j < 4; ++j) {
            int col = n0 + wn + j * 16 + l16;
#pragma unroll
            for (int rg = 0; rg < 4; ++rg) {
                int r = rb + rg;
                float v = acc[i][j][rg];
                if (mode == 0) {
                    ((unsigned short*)C)[(size_t)r * Nc + col] = f2b(v);
                } else if (r < M) {
                    float s = fmaxf(nx[r] * na[col], 1e-6f);
                    ((float*)C)[(size_t)r * Nc + col] = v / s;
                }
            }
        }
    }
}

// ---------------- GCN aggregation: one wave per node, bf16 gather rows ----------------

__global__ __launch_bounds__(256) void k_agg(const unsigned short* __restrict__ xw, const int* __restrict__ off,
                                             const int* __restrict__ esrc, const float* __restrict__ enorm,
                                             const float* __restrict__ dis, const float* __restrict__ bias,
                                             void* __restrict__ out, int n, int do_relu, int out_bf16) {
    int node = (blockIdx.x * 256 + threadIdx.x) >> 6;
    int lane = threadIdx.x & 63;
    if (node >= n) return;
    float d = dis[node];
    float w0 = d * d;
    ushort4 u = ((const ushort4*)(xw + (size_t)node * HID))[lane];
    float a0 = w0 * b2f(u.x), a1 = w0 * b2f(u.y), a2 = w0 * b2f(u.z), a3 = w0 * b2f(u.w);
    int p = off[node], p1 = off[node + 1];
    for (; p + 1 < p1; p += 2) {
        int s0 = esrc[p], s1 = esrc[p + 1];
        float w_0 = enorm[p], w_1 = enorm[p + 1];
        ushort4 v0 = ((const ushort4*)(xw + (size_t)s0 * HID))[lane];
        ushort4 v1 = ((const ushort4*)(xw + (size_t)s1 * HID))[lane];
        a0 = fmaf(w_0, b2f(v0.x), a0); a1 = fmaf(w_0, b2f(v0.y), a1);
        a2 = fmaf(w_0, b2f(v0.z), a2); a3 = fmaf(w_0, b2f(v0.w), a3);
        a0 = fmaf(w_1, b2f(v1.x), a0); a1 = fmaf(w_1, b2f(v1.y), a1);
        a2 = fmaf(w_1, b2f(v1.z), a2); a3 = fmaf(w_1, b2f(v1.w), a3);
    }
    if (p < p1) {
        int s0 = esrc[p];
        float w_0 = enorm[p];
        ushort4 v0 = ((const ushort4*)(xw + (size_t)s0 * HID))[lane];
        a0 = fmaf(w_0, b2f(v0.x), a0); a1 = fmaf(w_0, b2f(v0.y), a1);
        a2 = fmaf(w_0, b2f(v0.z), a2); a3 = fmaf(w_0, b2f(v0.w), a3);
    }
    float4 b = ((const float4*)bias)[lane];
    a0 += b.x; a1 += b.y; a2 += b.z; a3 += b.w;
    if (do_relu) {
        a0 = fmaxf(a0, 0.f); a1 = fmaxf(a1, 0.f); a2 = fmaxf(a2, 0.f); a3 = fmaxf(a3, 0.f);
    }
    if (out_bf16) {
        ushort4 o; o.x = f2b(a0); o.y = f2b(a1); o.z = f2b(a2); o.w = f2b(a3);
        ((ushort4*)((unsigned short*)out + (size_t)node * HID))[lane] = o;
    } else {
        float4 o; o.x = a0; o.y = a1; o.z = a2; o.w = a3;
        ((float4*)((float*)out + (size_t)node * HID))[lane] = o;
    }
}

// ---------------- L2 row-normalize (in place) + bf16 copy + row norm nx ----------------

__global__ __launch_bounds__(256) void k_norm(float* __restrict__ h, unsigned short* __restrict__ hb,
                                              float* __restrict__ nx, int n) {
    int node = (blockIdx.x * 256 + threadIdx.x) >> 6;
    int lane = threadIdx.x & 63;
    if (node >= n) return;
    float4* row = reinterpret_cast<float4*>(h + (size_t)node * HID);
    float4 v = row[lane];
    float ss = v.x * v.x + v.y * v.y + v.z * v.z + v.w * v.w;
    for (int m = 32; m >= 1; m >>= 1) ss += __shfl_xor(ss, m, 64);
    float qn = sqrtf(ss);
    float4 hn;
    hn.x = v.x / qn; hn.y = v.y / qn; hn.z = v.z / qn; hn.w = v.w / qn;
    float s2 = hn.x * hn.x + hn.y * hn.y + hn.z * hn.z + hn.w * hn.w;
    for (int m = 32; m >= 1; m >>= 1) s2 += __shfl_xor(s2, m, 64);
    row[lane] = hn;
    ushort4 o; o.x = f2b(hn.x); o.y = f2b(hn.y); o.z = f2b(hn.z); o.w = f2b(hn.w);
    ((ushort4*)(hb + (size_t)node * HID))[lane] = o;
    if (lane == 0) nx[node] = sqrtf(s2);
}

// ---------------- anchor gather: fp32 rows + bf16 rows + anchor norms ----------------

__global__ __launch_bounds__(256) void k_gather(const float* __restrict__ h, const int* __restrict__ prot,
                                                const float* __restrict__ nx,
                                                float* __restrict__ aR, unsigned short* __restrict__ aRb,
                                                float* __restrict__ na, int p_cnt) {
    int a = (blockIdx.x * 256 + threadIdx.x) >> 6;
    int lane = threadIdx.x & 63;
    if (a >= p_cnt) return;
    int p = prot[a];
    float4 v = *reinterpret_cast<const float4*>(h + (size_t)p * HID + lane * 4);
    *reinterpret_cast<float4*>(aR + (size_t)a * HID + lane * 4) = v;
    ushort4 o; o.x = f2b(v.x); o.y = f2b(v.y); o.z = f2b(v.z); o.w = f2b(v.w);
    ((ushort4*)(aRb + (size_t)a * HID))[lane] = o;
    if (lane == 0) na[a] = nx[p];
}

// ---------------- prototype head ----------------

__global__ __launch_bounds__(256) void k_proto(const float* __restrict__ aR, const float* __restrict__ Wl1,
                                               const float* __restrict__ bl1, const float* __restrict__ Wl2,
                                               const float* __restrict__ bl2, float* __restrict__ outp) {
    __shared__ float sa[HID];
    __shared__ float st[HID];
    int row = blockIdx.x, t = threadIdx.x;
    sa[t] = aR[(size_t)row * HID + t];
    __syncthreads();
    float acc = bl1[t];
#pragma unroll 8
    for (int k = 0; k < HID; ++k) acc = fmaf(sa[k], Wl1[k * HID + t], acc);
    st[t] = fmaxf(acc, 0.0f);
    __syncthreads();
    if (t < 64) {
        int c = t & 15, ch = t >> 4;
        float z = 0.f;
#pragma unroll 8
        for (int k = ch * 64; k < ch * 64 + 64; ++k) z = fmaf(st[k], Wl2[k * NCLS + c], z);
        z += __shfl_xor(z, 16, 64);
        z += __shfl_xor(z, 32, 64);
        z += bl2[c];
        float m = z;
        for (int d = 8; d >= 1; d >>= 1) m = fmaxf(m, __shfl_xor(m, d, 64));
        float e = expf(z - m);
        float s = e;
        for (int d = 8; d >= 1; d >>= 1) s += __shfl_xor(s, d, 64);
        if (t < 16) outp[row * NCLS + c] = z - m - logf(s);
    }
}

// ---------------- final: out = log_softmax(x_rel @ out_proto), LDS-staged ----------------

#define ONODES 8
__global__ __launch_bounds__(256) void k_out(const float* __restrict__ xrel, const float* __restrict__ proto,
                                             float* __restrict__ out, int n) {
    __shared__ __align__(16) float sp[NPROT * NCLS];        // 32 KB
    __shared__ __align__(16) float sx[ONODES][NPROT + 4];   // padded rows: spread banks
    int t = threadIdx.x;
#pragma unroll
    for (int i = 0; i < (NPROT * NCLS) / 1024; ++i) {       // 8 iters of float4
        int idx = i * 256 + t;
        float4 v = ((const float4*)proto)[idx];
        *(float4*)&sp[idx * 4] = v;
    }
    int node0 = blockIdx.x * ONODES;
#pragma unroll
    for (int i = 0; i < 4; ++i) {
        int idx = i * 256 + t;          // 0..1023 float4s, 128 per row
        int r = idx >> 7;
        int c4 = idx & 127;
        float4 v = ((const float4*)(xrel + (size_t)(node0 + r) * NPROT))[c4];
        sx[r][c4 * 4 + 0] = v.x; sx[r][c4 * 4 + 1] = v.y;
        sx[r][c4 * 4 + 2] = v.z; sx[r][c4 * 4 + 3] = v.w;
    }
    __syncthreads();
    if (t < ONODES * NCLS) {
        int c = t & 15, nl = t >> 4;
        float acc = 0.f;
#pragma unroll 4
        for (int p = 0; p < NPROT; ++p) acc = fmaf(sx[nl][p], sp[p * NCLS + c], acc);
        float m = acc;
        for (int d = 8; d >= 1; d >>= 1) m = fmaxf(m, __shfl_xor(m, d, 64));
        float e = expf(acc - m);
        float s = e;
        for (int d = 8; d >= 1; d >>= 1) s += __shfl_xor(s, d, 64);
        out[(size_t)(node0 + nl) * NCLS + c] = acc - m - logf(s);
    }
}

// ---------------- launch ----------------

extern "C" void kernel_launch(void* const* d_in, const int* in_sizes, int n_in,
                              void* d_out, int out_size, void* d_ws, size_t ws_size,
                              hipStream_t stream) {
    const float* x    = (const float*)d_in[0];
    const int*   eidx = (const int*)d_in[1];
    const int*   prot = (const int*)d_in[2];
    const float* W0  = (const float*)d_in[4];
    const float* b0  = (const float*)d_in[5];
    const float* W1  = (const float*)d_in[6];
    const float* b1  = (const float*)d_in[7];
    const float* Wl1 = (const float*)d_in[8];
    const float* bl1 = (const float*)d_in[9];
    const float* Wl2 = (const float*)d_in[10];
    const float* bl2 = (const float*)d_in[11];

    const int N = NN, E = EE;
    const int* esrc_in = eidx;
    const int* edst_in = eidx + E;

    // d_out layout: out [N,16] | x_rel [N,512] | out_proto [512,16]
    float* out_final = (float*)d_out;
    float* x_rel     = (float*)d_out + (size_t)N * NCLS;
    float* out_proto = x_rel + (size_t)N * NPROT;

    char* w = (char*)d_ws;
    auto alloc = [&](size_t bytes) { char* p = w; w += (bytes + 255) & ~(size_t)255; return p; };
    int*   cnt      = (int*)alloc((size_t)N * 4);
    int*   cursor   = (int*)alloc((size_t)N * 4);
    float* dis      = (float*)alloc((size_t)N * 4);
    int*   excl     = (int*)alloc((size_t)N * 4);
    int*   csr_off  = (int*)alloc((size_t)(N + 1) * 4);
    int*   bsum     = (int*)alloc(1024);
    int*   boff     = (int*)alloc(1024);
    int*   csr_src  = (int*)alloc((size_t)E * 4);
    float* csr_norm = (float*)alloc((size_t)E * 4);
    float* nx       = (float*)alloc((size_t)N * 4);
    float* na       = (float*)alloc((size_t)NPROT * 4);
    unsigned short* xb    = (unsigned short*)alloc((size_t)NP * DIN * 2);   // 12.8 MB
    unsigned short* Wt0   = (unsigned short*)alloc((size_t)HID * DIN * 2);
    unsigned short* Wt1   = (unsigned short*)alloc((size_t)HID * HID * 2);
    unsigned short* bufAb = (unsigned short*)alloc((size_t)NP * HID * 2);   // 25.6 MB (G1/G2 out; later hb)
    unsigned short* h0b   = (unsigned short*)alloc((size_t)NP * HID * 2);   // 25.6 MB
    float* aR       = (float*)alloc((size_t)NPROT * HID * 4);
    unsigned short* aRb   = (unsigned short*)alloc((size_t)NPROT * HID * 2);
    float* bufB     = x_rel;                 // fp32 [N,256] aliases x_rel region (dead before G3 stores)
    unsigned short* hb = bufAb;              // bf16 normalized h aliases bufAb (dead after agg2)

    hipMemsetAsync(cnt, 0, (size_t)N * 4, stream);
    hipMemsetAsync(cursor, 0, (size_t)N * 4, stream);

    // CSR build
    k_count<<<(E + 255) / 256, 256, 0, stream>>>(edst_in, cnt, E);
    k_dis<<<(N + 255) / 256, 256, 0, stream>>>(cnt, dis, N);
    int NB = (N + 255) / 256;
    k_scan1<<<NB, 256, 0, stream>>>(cnt, excl, bsum, N);
    k_scan2<<<1, 256, 0, stream>>>(bsum, boff, NB);
    k_scan3<<<NB, 256, 0, stream>>>(excl, boff, csr_off, N, E);
    k_fill<<<(E + 255) / 256, 256, 0, stream>>>(esrc_in, edst_in, csr_off, cursor, dis, csr_src, csr_norm, E);

    // casts
    k_cast<<<(N * DIN / 4 + 255) / 256, 256, 0, stream>>>(x, xb, N * DIN / 4);
    k_wt<<<(DIN * HID + 255) / 256, 256, 0, stream>>>(W0, Wt0, DIN, HID);
    k_wt<<<(HID * HID + 255) / 256, 256, 0, stream>>>(W1, Wt1, HID, HID);

    const int MT = NP / 128;  // 391

    // layer 1: h0 = relu(agg(x@W0) + b0)   (bf16 MFMA, bf16 messages)
    k_gemm_mfma<<<dim3(HID / 128, MT), 256, 0, stream>>>(xb, Wt0, bufAb, N, HID, DIN, 0, nullptr, nullptr);
    k_agg<<<N / 4, 256, 0, stream>>>(bufAb, csr_off, csr_src, csr_norm, dis, b0, h0b, N, 1, 1);

    // layer 2: h1 = agg(h0@W1) + b1
    k_gemm_mfma<<<dim3(HID / 128, MT), 256, 0, stream>>>(h0b, Wt1, bufAb, N, HID, HID, 0, nullptr, nullptr);
    k_agg<<<N / 4, 256, 0, stream>>>(bufAb, csr_off, csr_src, csr_norm, dis, b1, bufB, N, 0, 0);

    // normalize + anchors
    k_norm<<<N / 4, 256, 0, stream>>>(bufB, hb, nx, N);
    k_gather<<<NPROT / 4, 256, 0, stream>>>(bufB, prot, nx, aR, aRb, na, NPROT);

    // x_rel = (h @ anchors^T) / max(nx*na, eps)
    k_gemm_mfma<<<dim3(NPROT / 128, MT), 256, 0, stream>>>(hb, aRb, x_rel, N, NPROT, HID, 1, nx, na);

    // prototype head + final composition
    k_proto<<<NPROT, 256, 0, stream>>>(aR, Wl1, bl1, Wl2, bl2, out_proto);
    k_out<<<N / ONODES, 256, 0, stream>>>(x_rel, out_proto, out_final, N);
}

// Round 3
// 530.280 us; speedup vs baseline: 1.7464x; 1.1455x over previous
//
#include <hip/hip_runtime.h>
#include <hip/hip_bf16.h>
#include <math.h>

#define NN 50000
#define NP 50048          // padded to 128-multiple for MFMA tiles
#define EE 800000
#define DIN 128
#define HID 256
#define NCLS 16
#define NPROT 512

typedef __attribute__((ext_vector_type(8))) short short8;
typedef __attribute__((ext_vector_type(4))) float f32x4;

__device__ inline unsigned short f2b(float f) {
    union { float f; unsigned u; } c; c.f = f;
    unsigned u = c.u;
    unsigned r = (u + 0x7FFFu + ((u >> 16) & 1u)) >> 16;
    return (unsigned short)r;
}
__device__ inline float b2f(unsigned short u) {
    union { unsigned u; float f; } c; c.u = ((unsigned)u) << 16; return c.f;
}

// async global->LDS, 16B per lane; LDS dest must be wave-uniform base + lane*16
#define GL2LDS16(g, l)                                                              \
    __builtin_amdgcn_global_load_lds(                                               \
        (const __attribute__((address_space(1))) unsigned int*)(g),                 \
        (__attribute__((address_space(3))) unsigned int*)(l), 16, 0, 0)

// ---------------- degree / CSR construction ----------------

__global__ __launch_bounds__(256) void k_count(const int* __restrict__ dst, int* __restrict__ cnt, int e) {
    int i = blockIdx.x * 256 + threadIdx.x;
    if (i < e) atomicAdd(&cnt[dst[i]], 1);
}

__global__ __launch_bounds__(256) void k_dis(const int* __restrict__ cnt, float* __restrict__ dis, int n) {
    int i = blockIdx.x * 256 + threadIdx.x;
    if (i < n) dis[i] = rsqrtf((float)cnt[i] + 1.0f);
}

__global__ __launch_bounds__(256) void k_scan1(const int* __restrict__ cnt, int* __restrict__ excl,
                                               int* __restrict__ bsum, int n) {
    __shared__ int s[256];
    int t = threadIdx.x;
    int i = blockIdx.x * 256 + t;
    int v = (i < n) ? cnt[i] : 0;
    s[t] = v; __syncthreads();
    for (int d = 1; d < 256; d <<= 1) {
        int add = (t >= d) ? s[t - d] : 0;
        __syncthreads();
        s[t] += add;
        __syncthreads();
    }
    if (i < n) excl[i] = s[t] - v;
    if (t == 255) bsum[blockIdx.x] = s[255];
}

__global__ __launch_bounds__(256) void k_scan2(const int* __restrict__ bsum, int* __restrict__ boff, int nb) {
    __shared__ int s[256];
    int t = threadIdx.x;
    int v = (t < nb) ? bsum[t] : 0;
    s[t] = v; __syncthreads();
    for (int d = 1; d < 256; d <<= 1) {
        int add = (t >= d) ? s[t - d] : 0;
        __syncthreads();
        s[t] += add;
        __syncthreads();
    }
    if (t < nb) boff[t] = s[t] - v;
}

__global__ __launch_bounds__(256) void k_scan3(const int* __restrict__ excl, const int* __restrict__ boff,
                                               int* __restrict__ off, int n, int e) {
    int i = blockIdx.x * 256 + threadIdx.x;
    if (i < n) off[i] = excl[i] + boff[blockIdx.x];
    if (i == 0) off[n] = e;
}

__global__ __launch_bounds__(256) void k_fill(const int* __restrict__ src, const int* __restrict__ dst,
                                              const int* __restrict__ off, int* __restrict__ cursor,
                                              const float* __restrict__ dis,
                                              int* __restrict__ csr_src, float* __restrict__ csr_norm, int e) {
    int i = blockIdx.x * 256 + threadIdx.x;
    if (i >= e) return;
    int s = src[i], d = dst[i];
    int pos = atomicAdd(&cursor[d], 1);
    int slot = off[d] + pos;
    csr_src[slot] = s;
    csr_norm[slot] = dis[s] * dis[d];
}

// ---------------- casts / transposes ----------------

__global__ __launch_bounds__(256) void k_cast(const float* __restrict__ x, unsigned short* __restrict__ xb, int n4) {
    int i = blockIdx.x * 256 + threadIdx.x;
    if (i >= n4) return;
    float4 v = ((const float4*)x)[i];
    ushort4 o; o.x = f2b(v.x); o.y = f2b(v.y); o.z = f2b(v.z); o.w = f2b(v.w);
    ((ushort4*)xb)[i] = o;
}

// Wt[n*K+k] = bf16(W[k*N+n])
__global__ __launch_bounds__(256) void k_wt(const float* __restrict__ W, unsigned short* __restrict__ Wt,
                                            int K, int Nn) {
    int i = blockIdx.x * 256 + threadIdx.x;
    if (i >= K * Nn) return;
    int k = i / Nn, n = i - k * Nn;
    Wt[n * K + k] = f2b(W[(size_t)k * Nn + n]);
}

// ---------------- bf16 MFMA GEMM: C[M,Nc] = A[Mp,K] @ Bt[Nc,K]^T ----------------
// mode 0: store bf16 (unguarded, C padded).  mode 1: store fp32 with cosine scale, guarded r<M.
// Staging via global_load_lds width=16: unpadded stride-32 rows => LDS dest = t*16 bytes (wave-contiguous).

__global__ __launch_bounds__(256) void k_gemm_mfma(const unsigned short* __restrict__ A,
                                                   const unsigned short* __restrict__ Bt,
                                                   void* __restrict__ C, int M, int Nc, int K, int mode,
                                                   const float* __restrict__ nx, const float* __restrict__ na) {
    __shared__ __align__(16) unsigned short As[128 * 32];  // 8 KB, unpadded (required by global_load_lds)
    __shared__ __align__(16) unsigned short Bs[128 * 32];
    const int t = threadIdx.x;
    const int lane = t & 63;
    const int quad = lane >> 4;
    const int l16 = lane & 15;
    const int wv = t >> 6;
    const int wm = (wv & 1) * 64, wn = (wv >> 1) * 64;
    const int m0 = blockIdx.y * 128, n0 = blockIdx.x * 128;

    f32x4 acc[4][4];
#pragma unroll
    for (int i = 0; i < 4; ++i)
#pragma unroll
        for (int j = 0; j < 4; ++j)
#pragma unroll
            for (int r = 0; r < 4; ++r) acc[i][j][r] = 0.0f;

    const int sr = t >> 2;         // staging row 0..63 (per half)
    const int sc = (t & 3) * 8;    // short offset in row: 0,8,16,24

    for (int k0 = 0; k0 < K; k0 += 32) {
        // dest short index = sr*32 + sc = t*8 (bytes t*16): wave-uniform base + lane*16
        GL2LDS16(A + (size_t)(m0 + sr) * K + k0 + sc,       &As[t * 8]);
        GL2LDS16(A + (size_t)(m0 + 64 + sr) * K + k0 + sc,  &As[2048 + t * 8]);
        GL2LDS16(Bt + (size_t)(n0 + sr) * K + k0 + sc,      &Bs[t * 8]);
        GL2LDS16(Bt + (size_t)(n0 + 64 + sr) * K + k0 + sc, &Bs[2048 + t * 8]);
        __syncthreads();  // drains vmcnt
        short8 af[4], bf[4];
#pragma unroll
        for (int i = 0; i < 4; ++i)
            af[i] = *(const short8*)&As[(wm + i * 16 + l16) * 32 + quad * 8];
#pragma unroll
        for (int j = 0; j < 4; ++j)
            bf[j] = *(const short8*)&Bs[(wn + j * 16 + l16) * 32 + quad * 8];
#pragma unroll
        for (int i = 0; i < 4; ++i)
#pragma unroll
            for (int j = 0; j < 4; ++j)
                acc[i][j] = __builtin_amdgcn_mfma_f32_16x16x32_bf16(af[i], bf[j], acc[i][j], 0, 0, 0);
        __syncthreads();
    }

#pragma unroll
    for (int i = 0; i < 4; ++i) {
        int rb = m0 + wm + i * 16 + quad * 4;
#pragma unroll
        for (int j = 0; j < 4; ++j) {
            int col = n0 + wn + j * 16 + l16;
#pragma unroll
            for (int rg = 0; rg < 4; ++rg) {
                int r = rb + rg;
                float v = acc[i][j][rg];
                if (mode == 0) {
                    ((unsigned short*)C)[(size_t)r * Nc + col] = f2b(v);
                } else if (r < M) {
                    float s = fmaxf(nx[r] * na[col], 1e-6f);
                    ((float*)C)[(size_t)r * Nc + col] = v / s;
                }
            }
        }
    }
}

// ---------------- GCN aggregation: one wave per node, bf16 gather rows ----------------
// mode 1: +bias, relu, write bf16.   mode 2: +bias, L2-normalize row, write bf16 + nx.

__global__ __launch_bounds__(256) void k_agg(const unsigned short* __restrict__ xw, const int* __restrict__ off,
                                             const int* __restrict__ esrc, const float* __restrict__ enorm,
                                             const float* __restrict__ dis, const float* __restrict__ bias,
                                             unsigned short* __restrict__ out, float* __restrict__ nx,
                                             int n, int mode) {
    int node = (blockIdx.x * 256 + threadIdx.x) >> 6;
    int lane = threadIdx.x & 63;
    if (node >= n) return;
    float d = dis[node];
    float w0 = d * d;
    ushort4 u = ((const ushort4*)(xw + (size_t)node * HID))[lane];
    float a0 = w0 * b2f(u.x), a1 = w0 * b2f(u.y), a2 = w0 * b2f(u.z), a3 = w0 * b2f(u.w);
    int p = off[node], p1 = off[node + 1];
    for (; p + 1 < p1; p += 2) {
        int s0 = esrc[p], s1 = esrc[p + 1];
        float w_0 = enorm[p], w_1 = enorm[p + 1];
        ushort4 v0 = ((const ushort4*)(xw + (size_t)s0 * HID))[lane];
        ushort4 v1 = ((const ushort4*)(xw + (size_t)s1 * HID))[lane];
        a0 = fmaf(w_0, b2f(v0.x), a0); a1 = fmaf(w_0, b2f(v0.y), a1);
        a2 = fmaf(w_0, b2f(v0.z), a2); a3 = fmaf(w_0, b2f(v0.w), a3);
        a0 = fmaf(w_1, b2f(v1.x), a0); a1 = fmaf(w_1, b2f(v1.y), a1);
        a2 = fmaf(w_1, b2f(v1.z), a2); a3 = fmaf(w_1, b2f(v1.w), a3);
    }
    if (p < p1) {
        int s0 = esrc[p];
        float w_0 = enorm[p];
        ushort4 v0 = ((const ushort4*)(xw + (size_t)s0 * HID))[lane];
        a0 = fmaf(w_0, b2f(v0.x), a0); a1 = fmaf(w_0, b2f(v0.y), a1);
        a2 = fmaf(w_0, b2f(v0.z), a2); a3 = fmaf(w_0, b2f(v0.w), a3);
    }
    float4 b = ((const float4*)bias)[lane];
    a0 += b.x; a1 += b.y; a2 += b.z; a3 += b.w;
    if (mode == 1) {
        a0 = fmaxf(a0, 0.f); a1 = fmaxf(a1, 0.f); a2 = fmaxf(a2, 0.f); a3 = fmaxf(a3, 0.f);
    } else {
        // fused L2 row-normalize (reference: h /= ||h||, then nx = ||h_normed|| recomputed)
        float ss = a0 * a0 + a1 * a1 + a2 * a2 + a3 * a3;
        for (int m = 32; m >= 1; m >>= 1) ss += __shfl_xor(ss, m, 64);
        float qn = sqrtf(ss);
        a0 /= qn; a1 /= qn; a2 /= qn; a3 /= qn;
        float s2 = a0 * a0 + a1 * a1 + a2 * a2 + a3 * a3;
        for (int m = 32; m >= 1; m >>= 1) s2 += __shfl_xor(s2, m, 64);
        if (lane == 0) nx[node] = sqrtf(s2);
    }
    ushort4 o; o.x = f2b(a0); o.y = f2b(a1); o.z = f2b(a2); o.w = f2b(a3);
    ((ushort4*)(out + (size_t)node * HID))[lane] = o;
}

// ---------------- anchor gather (from bf16 h): fp32 rows + bf16 rows + anchor norms ----------------

__global__ __launch_bounds__(256) void k_gather(const unsigned short* __restrict__ hb, const int* __restrict__ prot,
                                                const float* __restrict__ nx,
                                                float* __restrict__ aR, unsigned short* __restrict__ aRb,
                                                float* __restrict__ na, int p_cnt) {
    int a = (blockIdx.x * 256 + threadIdx.x) >> 6;
    int lane = threadIdx.x & 63;
    if (a >= p_cnt) return;
    int p = prot[a];
    ushort4 v = ((const ushort4*)(hb + (size_t)p * HID))[lane];
    ((ushort4*)(aRb + (size_t)a * HID))[lane] = v;
    float4 f; f.x = b2f(v.x); f.y = b2f(v.y); f.z = b2f(v.z); f.w = b2f(v.w);
    *reinterpret_cast<float4*>(aR + (size_t)a * HID + lane * 4) = f;
    if (lane == 0) na[a] = nx[p];
}

// ---------------- prototype head ----------------

__global__ __launch_bounds__(256) void k_proto(const float* __restrict__ aR, const float* __restrict__ Wl1,
                                               const float* __restrict__ bl1, const float* __restrict__ Wl2,
                                               const float* __restrict__ bl2, float* __restrict__ outp) {
    __shared__ float sa[HID];
    __shared__ float st[HID];
    int row = blockIdx.x, t = threadIdx.x;
    sa[t] = aR[(size_t)row * HID + t];
    __syncthreads();
    float acc = bl1[t];
#pragma unroll 8
    for (int k = 0; k < HID; ++k) acc = fmaf(sa[k], Wl1[k * HID + t], acc);
    st[t] = fmaxf(acc, 0.0f);
    __syncthreads();
    if (t < 64) {
        int c = t & 15, ch = t >> 4;
        float z = 0.f;
#pragma unroll 8
        for (int k = ch * 64; k < ch * 64 + 64; ++k) z = fmaf(st[k], Wl2[k * NCLS + c], z);
        z += __shfl_xor(z, 16, 64);
        z += __shfl_xor(z, 32, 64);
        z += bl2[c];
        float m = z;
        for (int d = 8; d >= 1; d >>= 1) m = fmaxf(m, __shfl_xor(m, d, 64));
        float e = expf(z - m);
        float s = e;
        for (int d = 8; d >= 1; d >>= 1) s += __shfl_xor(s, d, 64);
        if (t < 16) outp[row * NCLS + c] = z - m - logf(s);
    }
}

// ---------------- final: out = log_softmax(x_rel @ out_proto) via MFMA ----------------
// M=NN rows, N=16 (one 16-wide tile), K=512. B-frags (proto^T) preloaded to registers;
// A-frags read directly from global (x_rel is L2/L3-hot from G3) and cast to bf16.

__global__ __launch_bounds__(256) void k_final(const float* __restrict__ xrel, const float* __restrict__ proto,
                                               float* __restrict__ out, int M) {
    __shared__ __align__(16) unsigned short pT[16 * 520];  // proto^T [c][k], padded stride
    int t = threadIdx.x;
    for (int i = t; i < NPROT * NCLS; i += 256) {
        int k = i >> 4, c = i & 15;
        pT[c * 520 + k] = f2b(proto[i]);
    }
    __syncthreads();
    const int lane = t & 63, wv = t >> 6;
    const int quad = lane >> 4, l16 = lane & 15;
    short8 bfr[16];
#pragma unroll
    for (int ks = 0; ks < 16; ++ks)
        bfr[ks] = *(const short8*)&pT[l16 * 520 + ks * 32 + quad * 8];
    int m0 = blockIdx.x * 128;
#pragma unroll
    for (int mt = 0; mt < 2; ++mt) {
        int tile0 = m0 + (wv * 2 + mt) * 16;
        int r = tile0 + l16;
        int rl = (r < M) ? r : (M - 1);   // clamp loads for padded tail rows
        const float* xr = xrel + (size_t)rl * NPROT + quad * 8;
        f32x4 acc = {0.f, 0.f, 0.f, 0.f};
#pragma unroll
        for (int ks = 0; ks < 16; ++ks) {
            float4 v0 = *(const float4*)(xr + ks * 32);
            float4 v1 = *(const float4*)(xr + ks * 32 + 4);
            short8 af;
            af[0] = (short)f2b(v0.x); af[1] = (short)f2b(v0.y);
            af[2] = (short)f2b(v0.z); af[3] = (short)f2b(v0.w);
            af[4] = (short)f2b(v1.x); af[5] = (short)f2b(v1.y);
            af[6] = (short)f2b(v1.z); af[7] = (short)f2b(v1.w);
            acc = __builtin_amdgcn_mfma_f32_16x16x32_bf16(af, bfr[ks], acc, 0, 0, 0);
        }
        // C layout: col=l16, row=quad*4+rg. log_softmax across the 16 cols = 16-lane shuffle group.
#pragma unroll
        for (int rg = 0; rg < 4; ++rg) {
            int row = tile0 + quad * 4 + rg;
            float z = acc[rg];
            float mx = z;
            for (int d = 8; d >= 1; d >>= 1) mx = fmaxf(mx, __shfl_xor(mx, d, 64));
            float e = expf(z - mx);
            float s = e;
            for (int d = 8; d >= 1; d >>= 1) s += __shfl_xor(s, d, 64);
            if (row < M) out[(size_t)row * NCLS + l16] = z - mx - logf(s);
        }
    }
}

// ---------------- launch ----------------

extern "C" void kernel_launch(void* const* d_in, const int* in_sizes, int n_in,
                              void* d_out, int out_size, void* d_ws, size_t ws_size,
                              hipStream_t stream) {
    const float* x    = (const float*)d_in[0];
    const int*   eidx = (const int*)d_in[1];
    const int*   prot = (const int*)d_in[2];
    const float* W0  = (const float*)d_in[4];
    const float* b0  = (const float*)d_in[5];
    const float* W1  = (const float*)d_in[6];
    const float* b1  = (const float*)d_in[7];
    const float* Wl1 = (const float*)d_in[8];
    const float* bl1 = (const float*)d_in[9];
    const float* Wl2 = (const float*)d_in[10];
    const float* bl2 = (const float*)d_in[11];

    const int N = NN, E = EE;
    const int* esrc_in = eidx;
    const int* edst_in = eidx + E;

    // d_out layout: out [N,16] | x_rel [N,512] | out_proto [512,16]
    float* out_final = (float*)d_out;
    float* x_rel     = (float*)d_out + (size_t)N * NCLS;
    float* out_proto = x_rel + (size_t)N * NPROT;

    char* w = (char*)d_ws;
    auto alloc = [&](size_t bytes) { char* p = w; w += (bytes + 255) & ~(size_t)255; return p; };
    int*   cnt      = (int*)alloc((size_t)N * 4);
    int*   cursor   = (int*)alloc((size_t)N * 4);
    float* dis      = (float*)alloc((size_t)N * 4);
    int*   excl     = (int*)alloc((size_t)N * 4);
    int*   csr_off  = (int*)alloc((size_t)(N + 1) * 4);
    int*   bsum     = (int*)alloc(1024);
    int*   boff     = (int*)alloc(1024);
    int*   csr_src  = (int*)alloc((size_t)E * 4);
    float* csr_norm = (float*)alloc((size_t)E * 4);
    float* nx       = (float*)alloc((size_t)N * 4);
    float* na       = (float*)alloc((size_t)NPROT * 4);
    unsigned short* xb    = (unsigned short*)alloc((size_t)NP * DIN * 2);   // 12.8 MB
    unsigned short* Wt0   = (unsigned short*)alloc((size_t)HID * DIN * 2);
    unsigned short* Wt1   = (unsigned short*)alloc((size_t)HID * HID * 2);
    unsigned short* bufAb = (unsigned short*)alloc((size_t)NP * HID * 2);   // 25.6 MB
    unsigned short* h0b   = (unsigned short*)alloc((size_t)NP * HID * 2);   // 25.6 MB
    float* aR       = (float*)alloc((size_t)NPROT * HID * 4);
    unsigned short* aRb   = (unsigned short*)alloc((size_t)NPROT * HID * 2);
    unsigned short* hb = h0b;   // h0b is dead after G2 reads it; reuse for normalized h (bf16)

    hipMemsetAsync(cnt, 0, (size_t)N * 4, stream);
    hipMemsetAsync(cursor, 0, (size_t)N * 4, stream);

    // CSR build
    k_count<<<(E + 255) / 256, 256, 0, stream>>>(edst_in, cnt, E);
    k_dis<<<(N + 255) / 256, 256, 0, stream>>>(cnt, dis, N);
    int NB = (N + 255) / 256;
    k_scan1<<<NB, 256, 0, stream>>>(cnt, excl, bsum, N);
    k_scan2<<<1, 256, 0, stream>>>(bsum, boff, NB);
    k_scan3<<<NB, 256, 0, stream>>>(excl, boff, csr_off, N, E);
    k_fill<<<(E + 255) / 256, 256, 0, stream>>>(esrc_in, edst_in, csr_off, cursor, dis, csr_src, csr_norm, E);

    // casts
    k_cast<<<(N * DIN / 4 + 255) / 256, 256, 0, stream>>>(x, xb, N * DIN / 4);
    k_wt<<<(DIN * HID + 255) / 256, 256, 0, stream>>>(W0, Wt0, DIN, HID);
    k_wt<<<(HID * HID + 255) / 256, 256, 0, stream>>>(W1, Wt1, HID, HID);

    const int MT = NP / 128;  // 391

    // layer 1: h0 = relu(agg(x@W0) + b0)
    k_gemm_mfma<<<dim3(HID / 128, MT), 256, 0, stream>>>(xb, Wt0, bufAb, N, HID, DIN, 0, nullptr, nullptr);
    k_agg<<<N / 4, 256, 0, stream>>>(bufAb, csr_off, csr_src, csr_norm, dis, b0, h0b, nullptr, N, 1);

    // layer 2: h = normalize(agg(h0@W1) + b1)   (norm fused into agg epilogue)
    k_gemm_mfma<<<dim3(HID / 128, MT), 256, 0, stream>>>(h0b, Wt1, bufAb, N, HID, HID, 0, nullptr, nullptr);
    k_agg<<<N / 4, 256, 0, stream>>>(bufAb, csr_off, csr_src, csr_norm, dis, b1, hb, nx, N, 2);

    // anchors
    k_gather<<<NPROT / 4, 256, 0, stream>>>(hb, prot, nx, aR, aRb, na, NPROT);

    // x_rel = (h @ anchors^T) / max(nx*na, eps)
    k_gemm_mfma<<<dim3(NPROT / 128, MT), 256, 0, stream>>>(hb, aRb, x_rel, N, NPROT, HID, 1, nx, na);

    // prototype head, then final composed log_softmax via MFMA
    k_proto<<<NPROT, 256, 0, stream>>>(aR, Wl1, bl1, Wl2, bl2, out_proto);
    k_final<<<MT, 256, 0, stream>>>(x_rel, out_proto, out_final, N);
}

// Round 4
// 489.486 us; speedup vs baseline: 1.8919x; 1.0833x over previous
//
#include <hip/hip_runtime.h>
#include <hip/hip_bf16.h>
#include <math.h>

#define NN 50000
#define NP 50048          // padded to 128-multiple for MFMA tiles
#define EE 800000
#define DIN 128
#define HID 256
#define NCLS 16
#define NPROT 512

typedef __attribute__((ext_vector_type(8))) short short8;
typedef __attribute__((ext_vector_type(4))) float f32x4;

__device__ inline unsigned short f2b(float f) {
    union { float f; unsigned u; } c; c.f = f;
    unsigned u = c.u;
    unsigned r = (u + 0x7FFFu + ((u >> 16) & 1u)) >> 16;
    return (unsigned short)r;
}
__device__ inline float b2f(unsigned short u) {
    union { unsigned u; float f; } c; c.u = ((unsigned)u) << 16; return c.f;
}

// async global->LDS, 16B per lane; LDS dest must be wave-uniform base + lane*16
#define GL2LDS16(g, l)                                                              \
    __builtin_amdgcn_global_load_lds(                                               \
        (const __attribute__((address_space(1))) unsigned int*)(g),                 \
        (__attribute__((address_space(3))) unsigned int*)(l), 16, 0, 0)

// ---------------- degree / CSR construction ----------------

__global__ __launch_bounds__(256) void k_count(const int* __restrict__ dst, int* __restrict__ cnt, int e) {
    int i = blockIdx.x * 256 + threadIdx.x;
    if (i < e) atomicAdd(&cnt[dst[i]], 1);
}

// block-local inclusive scan; also emits dis = rsqrt(deg+1)
__global__ __launch_bounds__(256) void k_scan1(const int* __restrict__ cnt, int* __restrict__ excl,
                                               int* __restrict__ bsum, float* __restrict__ dis, int n) {
    __shared__ int s[256];
    int t = threadIdx.x;
    int i = blockIdx.x * 256 + t;
    int v = (i < n) ? cnt[i] : 0;
    if (i < n) dis[i] = rsqrtf((float)v + 1.0f);
    s[t] = v; __syncthreads();
    for (int d = 1; d < 256; d <<= 1) {
        int add = (t >= d) ? s[t - d] : 0;
        __syncthreads();
        s[t] += add;
        __syncthreads();
    }
    if (i < n) excl[i] = s[t] - v;
    if (t == 255) bsum[blockIdx.x] = s[255];
}

__global__ __launch_bounds__(256) void k_scan2(const int* __restrict__ bsum, int* __restrict__ boff, int nb) {
    __shared__ int s[256];
    int t = threadIdx.x;
    int v = (t < nb) ? bsum[t] : 0;
    s[t] = v; __syncthreads();
    for (int d = 1; d < 256; d <<= 1) {
        int add = (t >= d) ? s[t - d] : 0;
        __syncthreads();
        s[t] += add;
        __syncthreads();
    }
    if (t < nb) boff[t] = s[t] - v;
}

__global__ __launch_bounds__(256) void k_scan3(const int* __restrict__ excl, const int* __restrict__ boff,
                                               int* __restrict__ off, int n, int e) {
    int i = blockIdx.x * 256 + threadIdx.x;
    if (i < n) off[i] = excl[i] + boff[blockIdx.x];
    if (i == 0) off[n] = e;
}

__global__ __launch_bounds__(256) void k_fill(const int* __restrict__ src, const int* __restrict__ dst,
                                              const int* __restrict__ off, int* __restrict__ cursor,
                                              const float* __restrict__ dis,
                                              int2* __restrict__ csr_e, int e) {
    int i = blockIdx.x * 256 + threadIdx.x;
    if (i >= e) return;
    int s = src[i], d = dst[i];
    int pos = atomicAdd(&cursor[d], 1);
    csr_e[off[d] + pos] = make_int2(s, __float_as_int(dis[s] * dis[d]));
}

// ---------------- fused prep: cast x -> bf16, transpose W0/W1 -> bf16 [n][k] ----------------

#define CAST_BLKS (NN * DIN / 4 / 256)   // 6250
#define WT0_BLKS  (DIN * HID / 256)      // 128
#define WT1_BLKS  (HID * HID / 256)      // 256

__global__ __launch_bounds__(256) void k_prep(const float* __restrict__ x, unsigned short* __restrict__ xb,
                                              const float* __restrict__ W0, unsigned short* __restrict__ Wt0,
                                              const float* __restrict__ W1, unsigned short* __restrict__ Wt1) {
    int b = blockIdx.x, t = threadIdx.x;
    if (b < CAST_BLKS) {
        int i = b * 256 + t;
        float4 v = ((const float4*)x)[i];
        ushort4 o; o.x = f2b(v.x); o.y = f2b(v.y); o.z = f2b(v.z); o.w = f2b(v.w);
        ((ushort4*)xb)[i] = o;
    } else if (b < CAST_BLKS + WT0_BLKS) {
        int i = (b - CAST_BLKS) * 256 + t;
        int k = i / HID, n = i - k * HID;
        Wt0[n * DIN + k] = f2b(W0[(size_t)k * HID + n]);
    } else {
        int i = (b - CAST_BLKS - WT0_BLKS) * 256 + t;
        int k = i / HID, n = i - k * HID;
        Wt1[n * HID + k] = f2b(W1[(size_t)k * HID + n]);
    }
}

// ---------------- bf16 MFMA GEMM: C[M,Nc] = A[Mp,K] @ Bt[Nc,K]^T ----------------
// mode 0: plain bf16 store (unguarded).  mode 1: fp32 cosine-scale store, guarded r<M.
// mode 2: +bias[col], relu, bf16 store (unguarded).

__global__ __launch_bounds__(256) void k_gemm_mfma(const unsigned short* __restrict__ A,
                                                   const unsigned short* __restrict__ Bt,
                                                   void* __restrict__ C, int M, int Nc, int K, int mode,
                                                   const float* __restrict__ nx, const float* __restrict__ na,
                                                   const float* __restrict__ bias) {
    __shared__ __align__(16) unsigned short As[128 * 32];  // 8 KB, unpadded (global_load_lds layout)
    __shared__ __align__(16) unsigned short Bs[128 * 32];
    const int t = threadIdx.x;
    const int lane = t & 63;
    const int quad = lane >> 4;
    const int l16 = lane & 15;
    const int wv = t >> 6;
    const int wm = (wv & 1) * 64, wn = (wv >> 1) * 64;
    const int m0 = blockIdx.y * 128, n0 = blockIdx.x * 128;

    f32x4 acc[4][4];
#pragma unroll
    for (int i = 0; i < 4; ++i)
#pragma unroll
        for (int j = 0; j < 4; ++j)
#pragma unroll
            for (int r = 0; r < 4; ++r) acc[i][j][r] = 0.0f;

    const int sr = t >> 2;         // staging row 0..63 (per half)
    const int sc = (t & 3) * 8;    // short offset in row: 0,8,16,24

    for (int k0 = 0; k0 < K; k0 += 32) {
        GL2LDS16(A + (size_t)(m0 + sr) * K + k0 + sc,       &As[t * 8]);
        GL2LDS16(A + (size_t)(m0 + 64 + sr) * K + k0 + sc,  &As[2048 + t * 8]);
        GL2LDS16(Bt + (size_t)(n0 + sr) * K + k0 + sc,      &Bs[t * 8]);
        GL2LDS16(Bt + (size_t)(n0 + 64 + sr) * K + k0 + sc, &Bs[2048 + t * 8]);
        __syncthreads();
        short8 af[4], bf[4];
#pragma unroll
        for (int i = 0; i < 4; ++i)
            af[i] = *(const short8*)&As[(wm + i * 16 + l16) * 32 + quad * 8];
#pragma unroll
        for (int j = 0; j < 4; ++j)
            bf[j] = *(const short8*)&Bs[(wn + j * 16 + l16) * 32 + quad * 8];
#pragma unroll
        for (int i = 0; i < 4; ++i)
#pragma unroll
            for (int j = 0; j < 4; ++j)
                acc[i][j] = __builtin_amdgcn_mfma_f32_16x16x32_bf16(af[i], bf[j], acc[i][j], 0, 0, 0);
        __syncthreads();
    }

#pragma unroll
    for (int i = 0; i < 4; ++i) {
        int rb = m0 + wm + i * 16 + quad * 4;
#pragma unroll
        for (int j = 0; j < 4; ++j) {
            int col = n0 + wn + j * 16 + l16;
#pragma unroll
            for (int rg = 0; rg < 4; ++rg) {
                int r = rb + rg;
                float v = acc[i][j][rg];
                if (mode == 0) {
                    ((unsigned short*)C)[(size_t)r * Nc + col] = f2b(v);
                } else if (mode == 2) {
                    v = fmaxf(v + bias[col], 0.0f);
                    ((unsigned short*)C)[(size_t)r * Nc + col] = f2b(v);
                } else if (r < M) {
                    float s = fmaxf(nx[r] * na[col], 1e-6f);
                    ((float*)C)[(size_t)r * Nc + col] = v / s;
                }
            }
        }
    }
}

// ---------------- GCN aggregation (128-dim, raw): one wave per node ----------------

__global__ __launch_bounds__(256) void k_agg128(const unsigned short* __restrict__ xw, const int* __restrict__ off,
                                                const int2* __restrict__ csr, const float* __restrict__ dis,
                                                unsigned short* __restrict__ out, int n) {
    int node = (blockIdx.x * 256 + threadIdx.x) >> 6;
    int lane = threadIdx.x & 63;
    if (node >= n) return;
    float d = dis[node];
    float w0 = d * d;
    ushort2 u = ((const ushort2*)(xw + (size_t)node * DIN))[lane];
    float a0 = w0 * b2f(u.x), a1 = w0 * b2f(u.y);
    int p = off[node], p1 = off[node + 1];
#define G128(e)                                                           \
    {                                                                     \
        ushort2 v = ((const ushort2*)(xw + (size_t)(e).x * DIN))[lane];   \
        float w = __int_as_float((e).y);                                  \
        a0 = fmaf(w, b2f(v.x), a0); a1 = fmaf(w, b2f(v.y), a1);           \
    }
    for (; p + 3 < p1; p += 4) {
        int2 e0 = csr[p], e1 = csr[p + 1], e2 = csr[p + 2], e3 = csr[p + 3];
        G128(e0) G128(e1) G128(e2) G128(e3)
    }
    for (; p < p1; ++p) { int2 e0 = csr[p]; G128(e0) }
#undef G128
    ushort2 o; o.x = f2b(a0); o.y = f2b(a1);
    ((ushort2*)(out + (size_t)node * DIN))[lane] = o;
}

// ---------------- GCN aggregation (256-dim): +bias then L2-normalize, emit bf16 + nx ----------------

__global__ __launch_bounds__(256) void k_agg256(const unsigned short* __restrict__ xw, const int* __restrict__ off,
                                                const int2* __restrict__ csr, const float* __restrict__ dis,
                                                const float* __restrict__ bias,
                                                unsigned short* __restrict__ out, float* __restrict__ nx, int n) {
    int node = (blockIdx.x * 256 + threadIdx.x) >> 6;
    int lane = threadIdx.x & 63;
    if (node >= n) return;
    float d = dis[node];
    float w0 = d * d;
    ushort4 u = ((const ushort4*)(xw + (size_t)node * HID))[lane];
    float a0 = w0 * b2f(u.x), a1 = w0 * b2f(u.y), a2 = w0 * b2f(u.z), a3 = w0 * b2f(u.w);
    int p = off[node], p1 = off[node + 1];
#define G256(e)                                                           \
    {                                                                     \
        ushort4 v = ((const ushort4*)(xw + (size_t)(e).x * HID))[lane];   \
        float w = __int_as_float((e).y);                                  \
        a0 = fmaf(w, b2f(v.x), a0); a1 = fmaf(w, b2f(v.y), a1);           \
        a2 = fmaf(w, b2f(v.z), a2); a3 = fmaf(w, b2f(v.w), a3);           \
    }
    for (; p + 3 < p1; p += 4) {
        int2 e0 = csr[p], e1 = csr[p + 1], e2 = csr[p + 2], e3 = csr[p + 3];
        G256(e0) G256(e1) G256(e2) G256(e3)
    }
    for (; p < p1; ++p) { int2 e0 = csr[p]; G256(e0) }
#undef G256
    float4 b = ((const float4*)bias)[lane];
    a0 += b.x; a1 += b.y; a2 += b.z; a3 += b.w;
    // fused L2 row-normalize (reference: h /= ||h||, nx = ||h_normed|| recomputed)
    float ss = a0 * a0 + a1 * a1 + a2 * a2 + a3 * a3;
    for (int m = 32; m >= 1; m >>= 1) ss += __shfl_xor(ss, m, 64);
    float qn = sqrtf(ss);
    a0 /= qn; a1 /= qn; a2 /= qn; a3 /= qn;
    float s2 = a0 * a0 + a1 * a1 + a2 * a2 + a3 * a3;
    for (int m = 32; m >= 1; m >>= 1) s2 += __shfl_xor(s2, m, 64);
    if (lane == 0) nx[node] = sqrtf(s2);
    ushort4 o; o.x = f2b(a0); o.y = f2b(a1); o.z = f2b(a2); o.w = f2b(a3);
    ((ushort4*)(out + (size_t)node * HID))[lane] = o;
}

// ---------------- fused anchor gather + prototype head ----------------
// block = one anchor: stage h[prot[b]] row, emit aRb (bf16 for G3) + na, then MLP + log_softmax.

__global__ __launch_bounds__(256) void k_gproto(const unsigned short* __restrict__ hb,
                                                const int* __restrict__ prot, const float* __restrict__ nx,
                                                unsigned short* __restrict__ aRb, float* __restrict__ na,
                                                const float* __restrict__ Wl1, const float* __restrict__ bl1,
                                                const float* __restrict__ Wl2, const float* __restrict__ bl2,
                                                float* __restrict__ outp) {
    __shared__ float sa[HID];
    __shared__ float st[HID];
    int row = blockIdx.x, t = threadIdx.x;
    int p = prot[row];
    unsigned short us = hb[(size_t)p * HID + t];
    aRb[(size_t)row * HID + t] = us;
    sa[t] = b2f(us);
    if (t == 0) na[row] = nx[p];
    __syncthreads();
    float acc = bl1[t];
#pragma unroll 8
    for (int k = 0; k < HID; ++k) acc = fmaf(sa[k], Wl1[k * HID + t], acc);
    st[t] = fmaxf(acc, 0.0f);
    __syncthreads();
    if (t < 64) {
        int c = t & 15, ch = t >> 4;
        float z = 0.f;
#pragma unroll 8
        for (int k = ch * 64; k < ch * 64 + 64; ++k) z = fmaf(st[k], Wl2[k * NCLS + c], z);
        z += __shfl_xor(z, 16, 64);
        z += __shfl_xor(z, 32, 64);
        z += bl2[c];
        float m = z;
        for (int d = 8; d >= 1; d >>= 1) m = fmaxf(m, __shfl_xor(m, d, 64));
        float e = expf(z - m);
        float s = e;
        for (int d = 8; d >= 1; d >>= 1) s += __shfl_xor(s, d, 64);
        if (t < 16) outp[row * NCLS + c] = z - m - logf(s);
    }
}

// ---------------- final: out = log_softmax(x_rel @ out_proto) via MFMA ----------------

__global__ __launch_bounds__(256) void k_final(const float* __restrict__ xrel, const float* __restrict__ proto,
                                               float* __restrict__ out, int M) {
    __shared__ __align__(16) unsigned short pT[16 * 520];  // proto^T [c][k], padded stride
    int t = threadIdx.x;
    for (int i = t; i < NPROT * NCLS; i += 256) {
        int k = i >> 4, c = i & 15;
        pT[c * 520 + k] = f2b(proto[i]);
    }
    __syncthreads();
    const int lane = t & 63, wv = t >> 6;
    const int quad = lane >> 4, l16 = lane & 15;
    short8 bfr[16];
#pragma unroll
    for (int ks = 0; ks < 16; ++ks)
        bfr[ks] = *(const short8*)&pT[l16 * 520 + ks * 32 + quad * 8];
    int m0 = blockIdx.x * 128;
#pragma unroll
    for (int mt = 0; mt < 2; ++mt) {
        int tile0 = m0 + (wv * 2 + mt) * 16;
        int r = tile0 + l16;
        int rl = (r < M) ? r : (M - 1);
        const float* xr = xrel + (size_t)rl * NPROT + quad * 8;
        f32x4 acc = {0.f, 0.f, 0.f, 0.f};
#pragma unroll
        for (int ks = 0; ks < 16; ++ks) {
            float4 v0 = *(const float4*)(xr + ks * 32);
            float4 v1 = *(const float4*)(xr + ks * 32 + 4);
            short8 af;
            af[0] = (short)f2b(v0.x); af[1] = (short)f2b(v0.y);
            af[2] = (short)f2b(v0.z); af[3] = (short)f2b(v0.w);
            af[4] = (short)f2b(v1.x); af[5] = (short)f2b(v1.y);
            af[6] = (short)f2b(v1.z); af[7] = (short)f2b(v1.w);
            acc = __builtin_amdgcn_mfma_f32_16x16x32_bf16(af, bfr[ks], acc, 0, 0, 0);
        }
#pragma unroll
        for (int rg = 0; rg < 4; ++rg) {
            int row = tile0 + quad * 4 + rg;
            float z = acc[rg];
            float mx = z;
            for (int d = 8; d >= 1; d >>= 1) mx = fmaxf(mx, __shfl_xor(mx, d, 64));
            float e = expf(z - mx);
            float s = e;
            for (int d = 8; d >= 1; d >>= 1) s += __shfl_xor(s, d, 64);
            if (row < M) out[(size_t)row * NCLS + l16] = z - mx - logf(s);
        }
    }
}

// ---------------- launch ----------------

extern "C" void kernel_launch(void* const* d_in, const int* in_sizes, int n_in,
                              void* d_out, int out_size, void* d_ws, size_t ws_size,
                              hipStream_t stream) {
    const float* x    = (const float*)d_in[0];
    const int*   eidx = (const int*)d_in[1];
    const int*   prot = (const int*)d_in[2];
    const float* W0  = (const float*)d_in[4];
    const float* b0  = (const float*)d_in[5];
    const float* W1  = (const float*)d_in[6];
    const float* b1  = (const float*)d_in[7];
    const float* Wl1 = (const float*)d_in[8];
    const float* bl1 = (const float*)d_in[9];
    const float* Wl2 = (const float*)d_in[10];
    const float* bl2 = (const float*)d_in[11];

    const int N = NN, E = EE;
    const int* esrc_in = eidx;
    const int* edst_in = eidx + E;

    // d_out layout: out [N,16] | x_rel [N,512] | out_proto [512,16]
    float* out_final = (float*)d_out;
    float* x_rel     = (float*)d_out + (size_t)N * NCLS;
    float* out_proto = x_rel + (size_t)N * NPROT;

    char* w = (char*)d_ws;
    auto alloc = [&](size_t bytes) { char* p = w; w += (bytes + 255) & ~(size_t)255; return p; };
    int*   cnt      = (int*)alloc((size_t)N * 4);
    int*   cursor   = (int*)alloc((size_t)N * 4);
    float* dis      = (float*)alloc((size_t)N * 4);
    int*   excl     = (int*)alloc((size_t)N * 4);
    int*   csr_off  = (int*)alloc((size_t)(N + 1) * 4);
    int*   bsum     = (int*)alloc(1024);
    int*   boff     = (int*)alloc(1024);
    int2*  csr_e    = (int2*)alloc((size_t)E * 8);
    float* nx       = (float*)alloc((size_t)N * 4);
    float* na       = (float*)alloc((size_t)NPROT * 4);
    unsigned short* xb    = (unsigned short*)alloc((size_t)NP * DIN * 2);   // 12.8 MB
    unsigned short* Wt0   = (unsigned short*)alloc((size_t)HID * DIN * 2);
    unsigned short* Wt1   = (unsigned short*)alloc((size_t)HID * HID * 2);
    unsigned short* bufAb = (unsigned short*)alloc((size_t)NP * HID * 2);   // 25.6 MB
    unsigned short* h0b   = (unsigned short*)alloc((size_t)NP * HID * 2);   // 25.6 MB
    unsigned short* aRb   = (unsigned short*)alloc((size_t)NPROT * HID * 2);
    unsigned short* a1 = bufAb;  // agg(x) [NP,128] bf16 — dead before G2 overwrites bufAb
    unsigned short* hb = h0b;    // normalized h — h0b dead once G2 has consumed it

    hipMemsetAsync(cnt, 0, (size_t)N * 4, stream);
    hipMemsetAsync(cursor, 0, (size_t)N * 4, stream);

    // CSR build
    k_count<<<(E + 255) / 256, 256, 0, stream>>>(edst_in, cnt, E);
    int NB = (N + 255) / 256;
    k_scan1<<<NB, 256, 0, stream>>>(cnt, excl, bsum, dis, N);
    k_scan2<<<1, 256, 0, stream>>>(bsum, boff, NB);
    k_scan3<<<NB, 256, 0, stream>>>(excl, boff, csr_off, N, E);
    k_fill<<<(E + 255) / 256, 256, 0, stream>>>(esrc_in, edst_in, csr_off, cursor, dis, csr_e, E);

    // prep: cast x, transpose weights (one fused launch)
    k_prep<<<CAST_BLKS + WT0_BLKS + WT1_BLKS, 256, 0, stream>>>(x, xb, W0, Wt0, W1, Wt1);

    const int MT = NP / 128;  // 391

    // layer 1 (flipped): a1 = agg(x);  h0 = relu(a1@W0 + b0)
    k_agg128<<<(N + 3) / 4, 256, 0, stream>>>(xb, csr_off, csr_e, dis, a1, N);
    k_gemm_mfma<<<dim3(HID / 128, MT), 256, 0, stream>>>(a1, Wt0, h0b, N, HID, DIN, 2, nullptr, nullptr, b0);

    // layer 2: h = normalize(agg(h0@W1) + b1)   (norm fused into agg epilogue)
    k_gemm_mfma<<<dim3(HID / 128, MT), 256, 0, stream>>>(h0b, Wt1, bufAb, N, HID, HID, 0, nullptr, nullptr, nullptr);
    k_agg256<<<(N + 3) / 4, 256, 0, stream>>>(bufAb, csr_off, csr_e, dis, b1, hb, nx, N);

    // anchors + prototype head (fused)
    k_gproto<<<NPROT, 256, 0, stream>>>(hb, prot, nx, aRb, na, Wl1, bl1, Wl2, bl2, out_proto);

    // x_rel = (h @ anchors^T) / max(nx*na, eps)
    k_gemm_mfma<<<dim3(NPROT / 128, MT), 256, 0, stream>>>(hb, aRb, x_rel, N, NPROT, HID, 1, nx, na, nullptr);

    // final composed log_softmax via MFMA
    k_final<<<MT, 256, 0, stream>>>(x_rel, out_proto, out_final, N);
}